// Round 3
// baseline (222.756 us; speedup 1.0000x reference)
//
#include <hip/hip_runtime.h>
#include <cstdint>
#include <cstddef>

// Problem dims (fixed by setup_inputs): b=4096, d=n=1024, k=4
#define NB 4096
#define ND 1024

typedef unsigned short ushortT;
typedef short short8 __attribute__((ext_vector_type(8)));
typedef float f32x4 __attribute__((ext_vector_type(4)));

__device__ __forceinline__ ushortT f2bf(float f) {
    unsigned u = __float_as_uint(f);
    u += 0x7FFFu + ((u >> 16) & 1u);      // round-to-nearest-even
    return (ushortT)(u >> 16);
}
__device__ __forceinline__ float bf2f(ushortT b) {
    return __uint_as_float(((unsigned)b) << 16);
}

__device__ __forceinline__ float block_sum_256(float v, float* red) {
    #pragma unroll
    for (int o = 32; o > 0; o >>= 1) v += __shfl_down(v, o, 64);
    int wave = threadIdx.x >> 6;
    if ((threadIdx.x & 63) == 0) red[wave] = v;
    __syncthreads();
    return red[0] + red[1] + red[2] + red[3];
}

// --- fused prep (vectorized): x->bf16 + ||x̂||² ; [mu;v]->bf16 + ||mû||², v̂·mû ;
//     zero BN stat accumulators ----------------------------------------------
__global__ void prep_all(const float* __restrict__ x,
                         const float* __restrict__ mu1, const float* __restrict__ v1,
                         const float* __restrict__ mu2, const float* __restrict__ v2,
                         ushortT* __restrict__ xh, ushortT* __restrict__ W1,
                         ushortT* __restrict__ W2,
                         float* __restrict__ xx1,
                         float* __restrict__ mm1, float* __restrict__ vmu1,
                         float* __restrict__ mm2, float* __restrict__ vmu2,
                         float* __restrict__ statz) {
    __shared__ float red[4];
    const int bid = blockIdx.x;
    const int t4 = threadIdx.x * 4;
    if (bid < 4096) {
        // x row -> bf16 + post-round norm
        const float* row = x + (size_t)bid * ND;
        float4 xv = *reinterpret_cast<const float4*>(row + t4);
        ushortT b0 = f2bf(xv.x), b1 = f2bf(xv.y), b2 = f2bf(xv.z), b3 = f2bf(xv.w);
        *reinterpret_cast<ushort4*>(xh + (size_t)bid * ND + t4) = make_ushort4(b0, b1, b2, b3);
        float r0 = bf2f(b0), r1 = bf2f(b1), r2 = bf2f(b2), r3 = bf2f(b3);
        float s = r0 * r0 + r1 * r1 + r2 * r2 + r3 * r3;
        float tot = block_sum_256(s, red);
        if (threadIdx.x == 0) xx1[bid] = tot;
    } else if (bid < 14336) {
        int bid2 = bid - 4096;
        const float* mu = (bid2 < 5120) ? mu1 : mu2;
        const float* v  = (bid2 < 5120) ? v1  : v2;
        ushortT* W      = (bid2 < 5120) ? W1  : W2;
        float* mm       = (bid2 < 5120) ? mm1 : mm2;
        float* vmu      = (bid2 < 5120) ? vmu1 : vmu2;
        if (bid2 >= 5120) bid2 -= 5120;
        int t = bid2 >> 10;            // panel 0..4
        int n = bid2 & 1023;
        const float* src = (t == 0) ? (mu + (size_t)n * ND)
                                    : (v + ((size_t)n * 4 + (t - 1)) * ND);
        const float* murow = mu + (size_t)n * ND;
        float4 sv = *reinterpret_cast<const float4*>(src + t4);
        float4 mv = *reinterpret_cast<const float4*>(murow + t4);
        ushortT b0 = f2bf(sv.x), b1 = f2bf(sv.y), b2 = f2bf(sv.z), b3 = f2bf(sv.w);
        *reinterpret_cast<ushort4*>(W + ((size_t)t * 1024 + n) * ND + t4) =
            make_ushort4(b0, b1, b2, b3);
        float s = bf2f(b0) * bf2f(f2bf(mv.x)) + bf2f(b1) * bf2f(f2bf(mv.y))
                + bf2f(b2) * bf2f(f2bf(mv.z)) + bf2f(b3) * bf2f(f2bf(mv.w));
        float tot = block_sum_256(s, red);
        if (threadIdx.x == 0) {
            if (t == 0) mm[n] = tot;
            else        vmu[n * 4 + (t - 1)] = tot;
        }
    } else {
        int z = bid - 14336;           // 0..3, zero 16KB of stats
        reinterpret_cast<float4*>(statz)[z * 256 + threadIdx.x] =
            make_float4(0.f, 0.f, 0.f, 0.f);
    }
}

// --- fused 5-panel HMU GEMM, 2-phase double-buffered -------------------------
// Tile 256(M) x 64(n) x 5 panels, BK=64, 8 waves (2M x 4N), dyn LDS 144KB.
// Wave (wm,wn) owns rows wm*128..+128 (8 mf) x cols wn*16..+16 x 5 panels.
// Per K-step: 9 global_load_lds -> s_waitcnt vmcnt(9) (counted, never 0 mid-loop)
// -> raw s_barrier -> 13 ds_read_b128 + 80 MFMA -> s_barrier.
// XOR slot swizzle (s = p ^ (row&7)); linear LDS dest, inverse-swz global src.
__launch_bounds__(512, 2)
__global__ void gemm_hmu(const ushortT* __restrict__ Xh, const ushortT* __restrict__ Wh,
                         const float* __restrict__ xx, const float* __restrict__ mm,
                         const float* __restrict__ vmu, const float* __restrict__ lam,
                         ushortT* __restrict__ Ub, float* __restrict__ Uf, int store_bf16,
                         float* __restrict__ sum, float* __restrict__ sumsq) {
    extern __shared__ ushortT lds[];   // 2 x (A:16384 + B:20480) ushorts
    const int tid = threadIdx.x;
    const int lane = tid & 63, wave = tid >> 6;
    const int wm = wave >> 2, wn = wave & 3;
    // XCD swizzle (assume hw xcd = bid&7): XCD x owns N-strips {2x, 2x+1}
    const int raw = blockIdx.x;
    const int xcd = raw & 7, slot = raw >> 3;
    const int n0 = (2 * xcd + (slot >> 4)) * 64;
    const int m0 = (slot & 15) * 256;

    f32x4 acc[8][5];
    #pragma unroll
    for (int mf = 0; mf < 8; ++mf)
        #pragma unroll
        for (int t = 0; t < 5; ++t)
            acc[mf][t] = (f32x4){0.f, 0.f, 0.f, 0.f};

    const int rbase = tid >> 3;        // 0..63 per 8KB round
    const int p = tid & 7;             // linear 16B slot

    auto stage = [&](int buf, int kt) {
        const int k0 = kt * 64;
        ushortT* Ad = lds + buf * 36864;
        ushortT* Bd = Ad + 16384;
        #pragma unroll
        for (int q = 0; q < 4; ++q) {          // A: 256 rows
            int row = q * 64 + rbase;
            int s = p ^ (row & 7);
            const ushortT* src = Xh + (size_t)(m0 + row) * ND + k0 + s * 8;
            __builtin_amdgcn_global_load_lds(
                (const __attribute__((address_space(1))) void*)src,
                (__attribute__((address_space(3))) void*)(Ad + (q * 64 + wave * 8) * 64),
                16, 0, 0);
        }
        #pragma unroll
        for (int q = 0; q < 5; ++q) {          // B: 320 stack rows
            int row = q * 64 + rbase;
            int t = row >> 6, rr = row & 63;
            int s = p ^ (row & 7);
            const ushortT* src = Wh + ((size_t)t * 1024 + n0 + rr) * ND + k0 + s * 8;
            __builtin_amdgcn_global_load_lds(
                (const __attribute__((address_space(1))) void*)src,
                (__attribute__((address_space(3))) void*)(Bd + (q * 64 + wave * 8) * 64),
                16, 0, 0);
        }
    };

    auto compute = [&](int buf) {
        const ushortT* Ab = lds + buf * 36864;
        const ushortT* Bb = Ab + 16384;
        #pragma unroll
        for (int i = 0; i < 2; ++i) {          // two K=32 substeps
            short8 av[8];
            #pragma unroll
            for (int mf = 0; mf < 8; ++mf) {
                int row = wm * 128 + mf * 16 + (lane & 15);
                int sl = (4 * i + (lane >> 4)) ^ (row & 7);
                av[mf] = *reinterpret_cast<const short8*>(&Ab[row * 64 + sl * 8]);
            }
            #pragma unroll
            for (int t = 0; t < 5; ++t) {
                int rr = wn * 16 + (lane & 15);
                int sl = (4 * i + (lane >> 4)) ^ (rr & 7);
                short8 bv = *reinterpret_cast<const short8*>(&Bb[(t * 64 + rr) * 64 + sl * 8]);
                #pragma unroll
                for (int mf = 0; mf < 8; ++mf)
                    acc[mf][t] = __builtin_amdgcn_mfma_f32_16x16x32_bf16(av[mf], bv, acc[mf][t], 0, 0, 0);
            }
        }
    };

    stage(0, 0);
    for (int kt = 0; kt < 15; ++kt) {
        stage((kt + 1) & 1, kt + 1);
        asm volatile("s_waitcnt vmcnt(9)" ::: "memory");  // prior tile done; 9 in flight
        __builtin_amdgcn_sched_barrier(0);
        __builtin_amdgcn_s_barrier();
        __builtin_amdgcn_sched_barrier(0);
        compute(kt & 1);
        __builtin_amdgcn_sched_barrier(0);
        __builtin_amdgcn_s_barrier();                     // reads done -> next overwrite safe
        __builtin_amdgcn_sched_barrier(0);
    }
    asm volatile("s_waitcnt vmcnt(0)" ::: "memory");
    __builtin_amdgcn_sched_barrier(0);
    __builtin_amdgcn_s_barrier();
    __builtin_amdgcn_sched_barrier(0);
    compute(1);

    // epilogue: u = expm1(-q/1024) via cubic (|x|<=0.07), fused column stats
    const int col = n0 + wn * 16 + (lane & 15);
    const float lamc = lam[col], mmc = mm[col];
    const float4 vm = *reinterpret_cast<const float4*>(vmu + col * 4);
    float csum = 0.f, csq = 0.f;
    #pragma unroll
    for (int mf = 0; mf < 8; ++mf) {
        #pragma unroll
        for (int i = 0; i < 4; ++i) {
            int brow = m0 + wm * 128 + mf * 16 + (lane >> 4) * 4 + i;
            float s0 = acc[mf][0][i];
            float p0 = acc[mf][1][i] - vm.x;
            float p1 = acc[mf][2][i] - vm.y;
            float p2 = acc[mf][3][i] - vm.z;
            float p3 = acc[mf][4][i] - vm.w;
            float q = lamc * (xx[brow] - 2.f * s0 + mmc)
                    + p0 * p0 + p1 * p1 + p2 * p2 + p3 * p3;
            float xq = q * (1.0f / 1024.0f);
            float u = -xq * (1.0f - xq * (0.5f - xq * 0.16666667f));  // expm1(-x)
            float ur;
            if (store_bf16) {
                ushortT ub = f2bf(u);
                Ub[(size_t)brow * ND + col] = ub;
                ur = bf2f(ub);
            } else {
                Uf[(size_t)brow * ND + col] = u;
                ur = u;
            }
            csum += ur; csq += ur * ur;
        }
    }
    csum += __shfl_xor(csum, 16); csum += __shfl_xor(csum, 32);
    csq  += __shfl_xor(csq, 16);  csq  += __shfl_xor(csq, 32);
    if (lane < 16) {
        atomicAdd(&sum[col], csum);
        atomicAdd(&sumsq[col], csq);
    }
}

// --- BN apply (finalize inlined) -> h (bf16) + post-round row norms ----------
__global__ void bn_apply_h(const ushortT* __restrict__ U, const float* __restrict__ sum,
                           const float* __restrict__ sumsq, const float* __restrict__ g,
                           const float* __restrict__ beta, ushortT* __restrict__ hh,
                           float* __restrict__ xx2) {
    __shared__ float red[4];
    const int r = blockIdx.x;
    const int t = threadIdx.x;
    ushort4 uv = reinterpret_cast<const ushort4*>(U + (size_t)r * ND)[t];
    float4 sv = reinterpret_cast<const float4*>(sum)[t];
    float4 qv = reinterpret_cast<const float4*>(sumsq)[t];
    float4 gv = reinterpret_cast<const float4*>(g)[t];
    float4 bv = reinterpret_cast<const float4*>(beta)[t];
    float s = 0.f;
    ushortT hb[4];
    float uarr[4] = {bf2f(uv.x), bf2f(uv.y), bf2f(uv.z), bf2f(uv.w)};
    float sarr[4] = {sv.x, sv.y, sv.z, sv.w};
    float qarr[4] = {qv.x, qv.y, qv.z, qv.w};
    float garr[4] = {gv.x, gv.y, gv.z, gv.w};
    float barr[4] = {bv.x, bv.y, bv.z, bv.w};
    #pragma unroll
    for (int j = 0; j < 4; ++j) {
        float m = sarr[j] * (1.0f / 4096.0f);
        float var = qarr[j] * (1.0f / 4096.0f) - m * m;
        float a = rsqrtf(var + 1e-5f) * garr[j];
        float h = (uarr[j] - m) * a + barr[j];
        hb[j] = f2bf(h);
        float hr = bf2f(hb[j]);
        s += hr * hr;
    }
    reinterpret_cast<ushort4*>(hh + (size_t)r * ND)[t] = make_ushort4(hb[0], hb[1], hb[2], hb[3]);
    float tot = block_sum_256(s, red);
    if (threadIdx.x == 0) xx2[r] = tot;
}

// --- BN apply 2 (finalize inlined) + identity shortcut -----------------------
__global__ void bn_apply_out(const float* __restrict__ U, const float* __restrict__ sum,
                             const float* __restrict__ sumsq, const float* __restrict__ g,
                             const float* __restrict__ beta, const float* __restrict__ x,
                             float* __restrict__ out) {
    const int r = blockIdx.x;
    const int t = threadIdx.x;
    float4 uv = reinterpret_cast<const float4*>(U + (size_t)r * ND)[t];
    float4 xv = reinterpret_cast<const float4*>(x + (size_t)r * ND)[t];
    float4 sv = reinterpret_cast<const float4*>(sum)[t];
    float4 qv = reinterpret_cast<const float4*>(sumsq)[t];
    float4 gv = reinterpret_cast<const float4*>(g)[t];
    float4 bv = reinterpret_cast<const float4*>(beta)[t];
    float4 ov;
    {
        float m = sv.x * (1.0f / 4096.0f), var = qv.x * (1.0f / 4096.0f) - m * m;
        float a = rsqrtf(var + 1e-5f) * gv.x; ov.x = (uv.x - m) * a + bv.x + xv.x;
    }
    {
        float m = sv.y * (1.0f / 4096.0f), var = qv.y * (1.0f / 4096.0f) - m * m;
        float a = rsqrtf(var + 1e-5f) * gv.y; ov.y = (uv.y - m) * a + bv.y + xv.y;
    }
    {
        float m = sv.z * (1.0f / 4096.0f), var = qv.z * (1.0f / 4096.0f) - m * m;
        float a = rsqrtf(var + 1e-5f) * gv.z; ov.z = (uv.z - m) * a + bv.z + xv.z;
    }
    {
        float m = sv.w * (1.0f / 4096.0f), var = qv.w * (1.0f / 4096.0f) - m * m;
        float a = rsqrtf(var + 1e-5f) * gv.w; ov.w = (uv.w - m) * a + bv.w + xv.w;
    }
    reinterpret_cast<float4*>(out + (size_t)r * ND)[t] = ov;
}

extern "C" void kernel_launch(void* const* d_in, const int* in_sizes, int n_in,
                              void* d_out, int out_size, void* d_ws, size_t ws_size,
                              hipStream_t stream) {
    const float* x    = (const float*)d_in[0];
    const float* mu1  = (const float*)d_in[1];
    const float* lam1 = (const float*)d_in[2];
    const float* v1   = (const float*)d_in[3];
    const float* g1   = (const float*)d_in[4];
    const float* b1   = (const float*)d_in[5];
    const float* mu2  = (const float*)d_in[6];
    const float* lam2 = (const float*)d_in[7];
    const float* v2   = (const float*)d_in[8];
    const float* g2   = (const float*)d_in[9];
    const float* b2   = (const float*)d_in[10];
    float* out = (float*)d_out;
    char* ws = (char*)d_ws;
    const size_t MB = 1024 * 1024;

    // workspace layout (lifetime-overlapped):
    // [0,8)MB xh ; [8,18)MB W1 ; U2(f32,16MB) aliases [0,16) after gemm1 retires xh/W1
    // [18,26)MB hh ; [26,36)MB W2 ; [36,44)MB U1(bf16) ; [44MB,..) stats
    ushortT* xh  = (ushortT*)(ws + 0);
    ushortT* W1  = (ushortT*)(ws + 8 * MB);
    float*   U2  = (float*)  (ws + 0);
    ushortT* hh  = (ushortT*)(ws + 18 * MB);
    ushortT* W2  = (ushortT*)(ws + 26 * MB);
    ushortT* U1  = (ushortT*)(ws + 36 * MB);
    char* st = ws + 44 * MB;
    float* xx1    = (float*)(st + 0);
    float* xx2    = (float*)(st + 16384);
    float* mm1    = (float*)(st + 32768);
    float* mm2    = (float*)(st + 36864);
    float* vmu1   = (float*)(st + 40960);
    float* vmu2   = (float*)(st + 57344);
    float* sum1   = (float*)(st + 73728);   // sum1,sumsq1,sum2,sumsq2 contiguous 16KB
    float* sumsq1 = (float*)(st + 77824);
    float* sum2   = (float*)(st + 81920);
    float* sumsq2 = (float*)(st + 86016);

    const size_t needed = 44 * MB + 90112;
    if (ws_size < needed) return;

    hipFuncSetAttribute((const void*)gemm_hmu,
                        hipFuncAttributeMaxDynamicSharedMemorySize, 147456);

    prep_all<<<14340, 256, 0, stream>>>(x, mu1, v1, mu2, v2, xh, W1, W2,
                                        xx1, mm1, vmu1, mm2, vmu2, sum1);

    gemm_hmu<<<256, 512, 147456, stream>>>(xh, W1, xx1, mm1, vmu1, lam1,
                                           U1, nullptr, 1, sum1, sumsq1);
    bn_apply_h<<<NB, 256, 0, stream>>>(U1, sum1, sumsq1, g1, b1, hh, xx2);

    gemm_hmu<<<256, 512, 147456, stream>>>(hh, W2, xx2, mm2, vmu2, lam2,
                                           nullptr, U2, 0, sum2, sumsq2);
    bn_apply_out<<<NB, 256, 0, stream>>>(U2, sum2, sumsq2, g2, b2, x, out);
}